// Round 1
// baseline (842.105 us; speedup 1.0000x reference)
//
#include <hip/hip_runtime.h>
#include <math.h>

#define B 128
#define D 512
#define S 512
#define TOPK 10

// -------- workspace layout (floats) --------
// g     [B*D]   @ 0
// gterm [B*D]   @ 65536
// C1    [S*D]   @ 131072
// score [B*S]   @ 393216
// total 458752 floats = 1.75 MB

// ---------------- transpose: feat[b,s,d] = x[b,d,s] ----------------
__global__ void transpose_kernel(const float* __restrict__ x, float* __restrict__ feat) {
    __shared__ float tile[32][33];
    int b = blockIdx.z;
    int s0 = blockIdx.x * 32, d0 = blockIdx.y * 32;
    int tx = threadIdx.x, ty = threadIdx.y;  // 32 x 8
    const float* xb = x + (size_t)b * D * S;
    float* fb = feat + (size_t)b * S * D;
#pragma unroll
    for (int j = 0; j < 4; ++j)
        tile[ty + j * 8][tx] = xb[(size_t)(d0 + ty + j * 8) * S + s0 + tx];
    __syncthreads();
#pragma unroll
    for (int j = 0; j < 4; ++j)
        fb[(size_t)(s0 + ty + j * 8) * D + d0 + tx] = tile[tx][ty + j * 8];
}

// ---------------- per-(b,d) mean over s: one wave per row ----------------
__global__ void mean_kernel(const float* __restrict__ x, float* __restrict__ g) {
    int wave = (int)((blockIdx.x * blockDim.x + threadIdx.x) >> 6);
    int lane = threadIdx.x & 63;
    const float4* row = (const float4*)(x + (size_t)wave * S);
    float4 a = row[lane];
    float4 c = row[lane + 64];
    float sum = a.x + a.y + a.z + a.w + c.x + c.y + c.z + c.w;
#pragma unroll
    for (int off = 32; off; off >>= 1) sum += __shfl_down(sum, off);
    if (lane == 0) g[wave] = sum * (1.0f / S);
}

// ---------------- score init to b2 ----------------
__global__ void score_init_kernel(float* __restrict__ score, const float* __restrict__ b2) {
    int i = blockIdx.x * 256 + threadIdx.x;
    score[i] = b2[0];
}

// ---------------- C1[s,d] = b1[d] + sum_f pe[s,f]*w1[f,d] ----------------
// pe[s,2i] = sin(s*e_i), pe[s,2i+1] = cos(s*e_i), e_i = exp(2i * (-ln(10000)/1024))
__global__ void c1_kernel(const float* __restrict__ w1, const float* __restrict__ b1,
                          float* __restrict__ C1) {
    __shared__ float sv[8][512];
    __shared__ float cv[8][512];
    int t = threadIdx.x;
    int s0 = blockIdx.x * 8;
    int d = blockIdx.y * 256 + t;
#pragma unroll
    for (int q = 0; q < 16; ++q) {
        int e = t + 256 * q;  // 0..4095
        int r = e >> 9;       // local s row 0..7
        int i = e & 511;
        float ei = expf((float)(2 * i) * -0.0089944730195f);  // -ln(10000)/1024 * 2i
        float ang = (float)(s0 + r) * ei;
        sv[r][i] = sinf(ang);
        cv[r][i] = cosf(ang);
    }
    __syncthreads();
    float acc[8] = {0.f, 0.f, 0.f, 0.f, 0.f, 0.f, 0.f, 0.f};
    for (int i = 0; i < 512; ++i) {
        float ws = w1[(size_t)(2 * i) * D + d];
        float wc = w1[(size_t)(2 * i + 1) * D + d];
#pragma unroll
        for (int r = 0; r < 8; ++r) acc[r] += sv[r][i] * ws + cv[r][i] * wc;
    }
    float bb = b1[d];
#pragma unroll
    for (int r = 0; r < 8; ++r) C1[(size_t)(s0 + r) * D + d] = acc[r] + bb;
}

// ---------------- gterm[b,d] = sum_k g[b,k] * w1[D+k, d] ----------------
__global__ void gterm_kernel(const float* __restrict__ g, const float* __restrict__ w1,
                             float* __restrict__ gterm) {
    int b = blockIdx.x;
    int d = blockIdx.y * 256 + threadIdx.x;
    const float* gb = g + b * D;
    float acc = 0.f;
    for (int k = 0; k < D; ++k) acc += gb[k] * w1[(size_t)(D + k) * D + d];
    gterm[b * D + d] = acc;
}

// ---------------- main fused GEMM + ReLU + w2-dot -> atomic score ----------------
// rows = (b,s) pairs; A[row,k] = x[b,k,s]; Bmat = w1[0:D,:]
#define BM 128
#define BN 128
#define BK 16
__global__ __launch_bounds__(256) void gemm_kernel(
    const float* __restrict__ x, const float* __restrict__ w1,
    const float* __restrict__ w2, const float* __restrict__ gterm,
    const float* __restrict__ C1, float* __restrict__ score) {
    __shared__ float As[BK][BM];
    __shared__ float Bs[BK][BN];
    int t = threadIdx.x;
    int row0 = blockIdx.x * BM;  // 128 rows, always within one batch (512 % 128 == 0)
    int d0 = blockIdx.y * BN;
    int b = row0 >> 9;
    int s0 = row0 & 511;
    const float* xb = x + (size_t)b * D * S;
    int tr = t >> 4, tc = t & 15;
    float acc[8][8] = {};
    for (int k0 = 0; k0 < D; k0 += BK) {
#pragma unroll
        for (int q = 0; q < 8; ++q) {
            int e = t + 256 * q;  // 0..2047
            int k = e >> 7, r = e & 127;
            As[k][r] = xb[(size_t)(k0 + k) * S + s0 + r];
            Bs[k][r] = w1[(size_t)(k0 + k) * D + d0 + r];
        }
        __syncthreads();
#pragma unroll
        for (int kk = 0; kk < BK; ++kk) {
            float a[8], bf[8];
#pragma unroll
            for (int i = 0; i < 8; ++i) a[i] = As[kk][tr * 8 + i];
#pragma unroll
            for (int j = 0; j < 8; ++j) bf[j] = Bs[kk][tc * 8 + j];
#pragma unroll
            for (int i = 0; i < 8; ++i)
#pragma unroll
                for (int j = 0; j < 8; ++j) acc[i][j] += a[i] * bf[j];
        }
        __syncthreads();
    }
    // epilogue: z = acc + gterm + C1; partial = sum_j w2[j]*relu(z)
    float w2r[8];
#pragma unroll
    for (int j = 0; j < 8; ++j) w2r[j] = w2[d0 + tc * 8 + j];
    const float* gt = gterm + b * D + d0 + tc * 8;
#pragma unroll
    for (int i = 0; i < 8; ++i) {
        int r = tr * 8 + i;
        int srow = s0 + r;
        const float* c1r = C1 + (size_t)srow * D + d0 + tc * 8;
        float part = 0.f;
#pragma unroll
        for (int j = 0; j < 8; ++j) {
            float z = acc[i][j] + gt[j] + c1r[j];
            part += w2r[j] * fmaxf(z, 0.f);
        }
        // threads with the same tr are 16 consecutive lanes -> width-16 shuffle reduce
#pragma unroll
        for (int off = 8; off; off >>= 1) part += __shfl_down(part, off, 16);
        if (tc == 0) atomicAdd(&score[b * S + srow], part);
    }
}

// ---------------- per-batch top-10 + one-hot + gather ----------------
__global__ void topk_kernel(const float* __restrict__ score, const float* __restrict__ feat,
                            float* __restrict__ out_ind, float* __restrict__ out_sel) {
    __shared__ float work[512];
    __shared__ float wv[8];
    __shared__ int wi[8];
    __shared__ int topi[TOPK];
    int b = blockIdx.x, t = threadIdx.x;
    work[t] = score[b * S + t];
    __syncthreads();
    for (int it = 0; it < TOPK; ++it) {
        float v = work[t];
        int i = t;
#pragma unroll
        for (int off = 32; off; off >>= 1) {
            float ov = __shfl_down(v, off);
            int oi = __shfl_down(i, off);
            if (ov > v || (ov == v && oi < i)) { v = ov; i = oi; }
        }
        if ((t & 63) == 0) { wv[t >> 6] = v; wi[t >> 6] = i; }
        __syncthreads();
        if (t == 0) {
            float bv = wv[0];
            int bi = wi[0];
            for (int w = 1; w < 8; ++w)
                if (wv[w] > bv || (wv[w] == bv && wi[w] < bi)) { bv = wv[w]; bi = wi[w]; }
            topi[it] = bi;
            work[bi] = -INFINITY;
        }
        __syncthreads();
    }
    if (t == 0) {  // sort indices ascending (matches idx = sort(idx))
        for (int a = 1; a < TOPK; ++a) {
            int key = topi[a];
            int c = a - 1;
            while (c >= 0 && topi[c] > key) { topi[c + 1] = topi[c]; --c; }
            topi[c + 1] = key;
        }
    }
    __syncthreads();
    float* oi_b = out_ind + (size_t)b * TOPK * S;
#pragma unroll
    for (int k = 0; k < TOPK; ++k) oi_b[k * S + t] = 0.0f;
    __syncthreads();
    if (t < TOPK) oi_b[t * S + topi[t]] = 1.0f;
    float* os_b = out_sel + (size_t)b * TOPK * D;
    const float* fb = feat + (size_t)b * S * D;
#pragma unroll
    for (int k = 0; k < TOPK; ++k) os_b[k * D + t] = fb[(size_t)topi[k] * D + t];
}

extern "C" void kernel_launch(void* const* d_in, const int* in_sizes, int n_in,
                              void* d_out, int out_size, void* d_ws, size_t ws_size,
                              hipStream_t stream) {
    const float* x  = (const float*)d_in[0];
    const float* w1 = (const float*)d_in[1];
    const float* b1 = (const float*)d_in[2];
    const float* w2 = (const float*)d_in[3];
    const float* b2 = (const float*)d_in[4];

    float* out = (float*)d_out;
    float* out_ind = out;                              // [B,10,S]
    float* out_sel = out + (size_t)B * TOPK * S;       // [B,10,D]
    float* feat    = out + 2 * (size_t)B * TOPK * S;   // [B,S,D]

    float* ws    = (float*)d_ws;
    float* g     = ws;
    float* gterm = ws + B * D;
    float* C1    = ws + 2 * B * D;
    float* score = ws + 2 * B * D + S * D;

    transpose_kernel<<<dim3(S / 32, D / 32, B), dim3(32, 8), 0, stream>>>(x, feat);
    mean_kernel<<<(B * D) / 4, 256, 0, stream>>>(x, g);
    score_init_kernel<<<(B * S) / 256, 256, 0, stream>>>(score, b2);
    c1_kernel<<<dim3(S / 8, D / 256), 256, 0, stream>>>(w1, b1, C1);
    gterm_kernel<<<dim3(B, D / 256), 256, 0, stream>>>(g, w1, gterm);
    gemm_kernel<<<dim3((B * S) / BM, D / BN), 256, 0, stream>>>(x, w1, w2, gterm, C1, score);
    topk_kernel<<<B, 512, 0, stream>>>(score, feat, out_ind, out_sel);
}

// Round 3
// 544.396 us; speedup vs baseline: 1.5469x; 1.5469x over previous
//
#include <hip/hip_runtime.h>
#include <math.h>

#define B 128
#define D 512
#define S 512
#define TOPK 10

typedef short bf16x8 __attribute__((ext_vector_type(8)));
typedef float f32x4 __attribute__((ext_vector_type(4)));
typedef short short4v __attribute__((ext_vector_type(4)));

// -------- workspace layout (floats) --------
// g/score [B*S=65536] @ 0         (g dead after gterm; score aliases it, zeroed then)
// gterm   [B*D=65536] @ 65536
// C1      [S*D]       @ 131072    (262144 floats)
// w1th    [512*512 bf16] @ 393216
// w1tl    [512*512 bf16] @ 524288
// total 655360 floats = 2.5 MB

// ---------------- transpose: feat[b,s,d] = x[b,d,s] ----------------
__global__ void transpose_kernel(const float* __restrict__ x, float* __restrict__ feat) {
    __shared__ float tile[32][33];
    int b = blockIdx.z;
    int s0 = blockIdx.x * 32, d0 = blockIdx.y * 32;
    int tx = threadIdx.x, ty = threadIdx.y;  // 32 x 8
    const float* xb = x + (size_t)b * D * S;
    float* fb = feat + (size_t)b * S * D;
#pragma unroll
    for (int j = 0; j < 4; ++j)
        tile[ty + j * 8][tx] = xb[(size_t)(d0 + ty + j * 8) * S + s0 + tx];
    __syncthreads();
#pragma unroll
    for (int j = 0; j < 4; ++j)
        fb[(size_t)(s0 + ty + j * 8) * D + d0 + tx] = tile[tx][ty + j * 8];
}

// ---------------- per-(b,d) mean over s: one wave per row ----------------
__global__ void mean_kernel(const float* __restrict__ x, float* __restrict__ g) {
    int wave = (int)((blockIdx.x * blockDim.x + threadIdx.x) >> 6);
    int lane = threadIdx.x & 63;
    const float4* row = (const float4*)(x + (size_t)wave * S);
    float4 a = row[lane];
    float4 c = row[lane + 64];
    float sum = a.x + a.y + a.z + a.w + c.x + c.y + c.z + c.w;
#pragma unroll
    for (int off = 32; off; off >>= 1) sum += __shfl_down(sum, off);
    if (lane == 0) g[wave] = sum * (1.0f / S);
}

// ---------------- split fp32 -> (hi bf16 RNE, lo bf16 RZ), packed hi|lo<<16 ----------------
__device__ __forceinline__ unsigned splitf(float f) {
    unsigned u = __float_as_uint(f);
    unsigned rb = u + 0x7FFFu + ((u >> 16) & 1u);  // RNE to bf16
    float hf = __uint_as_float(rb & 0xFFFF0000u);
    unsigned u2 = __float_as_uint(f - hf);  // exact residual
    return (rb >> 16) | (u2 & 0xFFFF0000u); // lo16 = hi-bf16, hi16 = lo-bf16
}

// ---------------- w1 split+transpose: w1t{h,l}[d][k] = split(w1[k][d]), k<512 ----------------
__global__ void w1split_kernel(const float* __restrict__ w1, ushort* __restrict__ w1th,
                               ushort* __restrict__ w1tl) {
    __shared__ float tile[32][33];
    int k0 = blockIdx.x * 32, d0 = blockIdx.y * 32;
    int tx = threadIdx.x, ty = threadIdx.y;  // 32 x 8
#pragma unroll
    for (int j = 0; j < 4; ++j)
        tile[ty + j * 8][tx] = w1[(size_t)(k0 + ty + j * 8) * D + d0 + tx];
    __syncthreads();
#pragma unroll
    for (int j = 0; j < 4; ++j) {
        unsigned p = splitf(tile[tx][ty + j * 8]);
        size_t idx = (size_t)(d0 + ty + j * 8) * 512 + k0 + tx;
        w1th[idx] = (ushort)(p & 0xFFFFu);
        w1tl[idx] = (ushort)(p >> 16);
    }
}

// ---------------- C1[s,d] = b1[d] + sum_f pe[s,f]*w1[f,d] ----------------
__global__ void c1_kernel(const float* __restrict__ w1, const float* __restrict__ b1,
                          float* __restrict__ C1) {
    __shared__ float sv[8][512];
    __shared__ float cv[8][512];
    int t = threadIdx.x;
    int s0 = blockIdx.x * 8;
    int d = blockIdx.y * 256 + t;
#pragma unroll
    for (int q = 0; q < 16; ++q) {
        int e = t + 256 * q;  // 0..4095
        int r = e >> 9;       // local s row 0..7
        int i = e & 511;
        float ei = expf((float)(2 * i) * -0.0089944730195f);  // -ln(10000)/1024 * 2i
        float ang = (float)(s0 + r) * ei;
        sv[r][i] = sinf(ang);
        cv[r][i] = cosf(ang);
    }
    __syncthreads();
    float acc[8] = {0.f, 0.f, 0.f, 0.f, 0.f, 0.f, 0.f, 0.f};
    for (int i = 0; i < 512; ++i) {
        float ws = w1[(size_t)(2 * i) * D + d];
        float wc = w1[(size_t)(2 * i + 1) * D + d];
#pragma unroll
        for (int r = 0; r < 8; ++r) acc[r] += sv[r][i] * ws + cv[r][i] * wc;
    }
    float bb = b1[d];
#pragma unroll
    for (int r = 0; r < 8; ++r) C1[(size_t)(s0 + r) * D + d] = acc[r] + bb;
}

// ---------------- gterm[b,d] = sum_k g[b,k] * w1[D+k, d] ----------------
__global__ void gterm_kernel(const float* __restrict__ g, const float* __restrict__ w1,
                             float* __restrict__ gterm) {
    int b = blockIdx.x;
    int d = blockIdx.y * 256 + threadIdx.x;
    const float* gb = g + b * D;
    float a0 = 0.f, a1 = 0.f, a2 = 0.f, a3 = 0.f;
    for (int k = 0; k < D; k += 4) {
        a0 += gb[k + 0] * w1[(size_t)(D + k + 0) * D + d];
        a1 += gb[k + 1] * w1[(size_t)(D + k + 1) * D + d];
        a2 += gb[k + 2] * w1[(size_t)(D + k + 2) * D + d];
        a3 += gb[k + 3] * w1[(size_t)(D + k + 3) * D + d];
    }
    gterm[b * D + d] = (a0 + a1) + (a2 + a3);
}

// ---------------- zero score (ws poisoned 0xAA each launch) ----------------
__global__ void zero_kernel(float* __restrict__ p) {
    p[blockIdx.x * 256 + threadIdx.x] = 0.0f;
}

// ---------------- split-bf16 MFMA GEMM + fused ReLU + w2-dot -> atomic score ----
// A[row][k] = feat[row][k]  (row = b*512+s), B[n][k] = w1t{h,l}[d][k]
// C = A*B via Ah*Bh + Ah*Bl + Al*Bh  (AlBl ~ 2^-18, dropped)
#define GP 40  // LDS pitch (bf16 elems): 80 B rows -> 16B-aligned b128 frag reads
__global__ __launch_bounds__(256, 2) void gemm_mfma(
    const float* __restrict__ feat, const ushort* __restrict__ w1th,
    const ushort* __restrict__ w1tl, const float* __restrict__ w2,
    const float* __restrict__ gterm, const float* __restrict__ C1,
    float* __restrict__ score) {
    __shared__ short sAh[128 * GP];
    __shared__ short sAl[128 * GP];
    __shared__ short sBh[128 * GP];
    __shared__ short sBl[128 * GP];
    int t = threadIdx.x;
    int d0 = blockIdx.x * 128;   // 4 col-blocks, fast dim -> consecutive blocks share A tile
    int row0 = blockIdx.y * 128; // 512 row-blocks; block stays within one batch
    int b = row0 >> 9;
    int tm = t >> 3, tk4 = t & 7;
    int w = t >> 6, l = t & 63;
    int wr = w >> 1, wc = w & 1;
    int lc = l & 15, lg = l >> 4;

    f32x4 acc[4][4] = {};

    for (int k0 = 0; k0 < D; k0 += 32) {
        __syncthreads();
        // stage A (fp32 -> split bf16) and B (pre-split bf16 copy)
#pragma unroll
        for (int q = 0; q < 4; ++q) {
            int m = tm + 32 * q;
            const float4 v = *(const float4*)(feat + (size_t)(row0 + m) * D + k0 + tk4 * 4);
            unsigned p0 = splitf(v.x), p1 = splitf(v.y), p2 = splitf(v.z), p3 = splitf(v.w);
            short4v hi, lo;
            hi[0] = (short)(p0 & 0xFFFFu); lo[0] = (short)(p0 >> 16);
            hi[1] = (short)(p1 & 0xFFFFu); lo[1] = (short)(p1 >> 16);
            hi[2] = (short)(p2 & 0xFFFFu); lo[2] = (short)(p2 >> 16);
            hi[3] = (short)(p3 & 0xFFFFu); lo[3] = (short)(p3 >> 16);
            *(short4v*)(sAh + m * GP + tk4 * 4) = hi;
            *(short4v*)(sAl + m * GP + tk4 * 4) = lo;
            size_t widx = (size_t)(d0 + m) * 512 + k0 + tk4 * 4;
            *(short4v*)(sBh + m * GP + tk4 * 4) = *(const short4v*)(w1th + widx);
            *(short4v*)(sBl + m * GP + tk4 * 4) = *(const short4v*)(w1tl + widx);
        }
        __syncthreads();
        bf16x8 ah[4], al[4], bh[4], bl[4];
#pragma unroll
        for (int i = 0; i < 4; ++i) {
            int m = wr * 64 + i * 16 + lc;
            ah[i] = *(const bf16x8*)(sAh + m * GP + lg * 8);
            al[i] = *(const bf16x8*)(sAl + m * GP + lg * 8);
            int n = wc * 64 + i * 16 + lc;
            bh[i] = *(const bf16x8*)(sBh + n * GP + lg * 8);
            bl[i] = *(const bf16x8*)(sBl + n * GP + lg * 8);
        }
#pragma unroll
        for (int i = 0; i < 4; ++i)
#pragma unroll
            for (int j = 0; j < 4; ++j) {
                acc[i][j] = __builtin_amdgcn_mfma_f32_16x16x32_bf16(ah[i], bh[j], acc[i][j], 0, 0, 0);
                acc[i][j] = __builtin_amdgcn_mfma_f32_16x16x32_bf16(ah[i], bl[j], acc[i][j], 0, 0, 0);
                acc[i][j] = __builtin_amdgcn_mfma_f32_16x16x32_bf16(al[i], bh[j], acc[i][j], 0, 0, 0);
            }
    }
    // epilogue: z = acc + gterm + C1; per-row partial = sum_d w2[d]*relu(z)
    float w2v[4], gt[4];
#pragma unroll
    for (int j = 0; j < 4; ++j) {
        int d = d0 + wc * 64 + j * 16 + lc;
        w2v[j] = w2[d];
        gt[j] = gterm[b * D + d];
    }
#pragma unroll
    for (int i = 0; i < 4; ++i)
#pragma unroll
        for (int reg = 0; reg < 4; ++reg) {
            int srow = row0 + wr * 64 + i * 16 + lg * 4 + reg;  // global row = b*S+s
            int s = srow & 511;
            float part = 0.f;
#pragma unroll
            for (int j = 0; j < 4; ++j) {
                int d = d0 + wc * 64 + j * 16 + lc;
                float z = acc[i][j][reg] + gt[j] + C1[(size_t)s * D + d];
                part += w2v[j] * fmaxf(z, 0.f);
            }
#pragma unroll
            for (int off = 8; off; off >>= 1) part += __shfl_down(part, off, 16);
            if (lc == 0) atomicAdd(&score[srow], part);
        }
}

// ---------------- per-batch top-10 + one-hot + gather ----------------
__global__ void topk_kernel(const float* __restrict__ score, const float* __restrict__ feat,
                            float* __restrict__ out_ind, float* __restrict__ out_sel) {
    __shared__ float work[512];
    __shared__ float wv[8];
    __shared__ int wi[8];
    __shared__ int topi[TOPK];
    int b = blockIdx.x, t = threadIdx.x;
    work[t] = score[b * S + t];
    __syncthreads();
    for (int it = 0; it < TOPK; ++it) {
        float v = work[t];
        int i = t;
#pragma unroll
        for (int off = 32; off; off >>= 1) {
            float ov = __shfl_down(v, off);
            int oi = __shfl_down(i, off);
            if (ov > v || (ov == v && oi < i)) { v = ov; i = oi; }
        }
        if ((t & 63) == 0) { wv[t >> 6] = v; wi[t >> 6] = i; }
        __syncthreads();
        if (t == 0) {
            float bv = wv[0];
            int bi = wi[0];
            for (int w = 1; w < 8; ++w)
                if (wv[w] > bv || (wv[w] == bv && wi[w] < bi)) { bv = wv[w]; bi = wi[w]; }
            topi[it] = bi;
            work[bi] = -INFINITY;
        }
        __syncthreads();
    }
    if (t == 0) {  // sort indices ascending (matches idx = sort(idx))
        for (int a = 1; a < TOPK; ++a) {
            int key = topi[a];
            int c = a - 1;
            while (c >= 0 && topi[c] > key) { topi[c + 1] = topi[c]; --c; }
            topi[c + 1] = key;
        }
    }
    __syncthreads();
    float* oi_b = out_ind + (size_t)b * TOPK * S;
#pragma unroll
    for (int k = 0; k < TOPK; ++k) oi_b[k * S + t] = 0.0f;
    __syncthreads();
    if (t < TOPK) oi_b[t * S + topi[t]] = 1.0f;
    float* os_b = out_sel + (size_t)b * TOPK * D;
    const float* fb = feat + (size_t)b * S * D;
#pragma unroll
    for (int k = 0; k < TOPK; ++k) os_b[k * D + t] = fb[(size_t)topi[k] * D + t];
}

extern "C" void kernel_launch(void* const* d_in, const int* in_sizes, int n_in,
                              void* d_out, int out_size, void* d_ws, size_t ws_size,
                              hipStream_t stream) {
    const float* x  = (const float*)d_in[0];
    const float* w1 = (const float*)d_in[1];
    const float* b1 = (const float*)d_in[2];
    const float* w2 = (const float*)d_in[3];
    // b2 (d_in[4]) is a uniform shift of all scores -> ranking-invariant, dropped.

    float* out = (float*)d_out;
    float* out_ind = out;                              // [B,10,S]
    float* out_sel = out + (size_t)B * TOPK * S;       // [B,10,D]
    float* feat    = out + 2 * (size_t)B * TOPK * S;   // [B,S,D]

    float* ws      = (float*)d_ws;
    float* g       = ws;                    // [B*D], dead after gterm
    float* score   = ws;                    // aliases g
    float* gterm   = ws + 65536;            // [B*D]
    float* C1      = ws + 131072;           // [S*D]
    ushort* w1th   = (ushort*)(ws + 393216);  // [512*512] bf16
    ushort* w1tl   = (ushort*)(ws + 524288);  // [512*512] bf16

    transpose_kernel<<<dim3(S / 32, D / 32, B), dim3(32, 8), 0, stream>>>(x, feat);
    mean_kernel<<<(B * D) / 4, 256, 0, stream>>>(x, g);
    w1split_kernel<<<dim3(16, 16), dim3(32, 8), 0, stream>>>(w1, w1th, w1tl);
    c1_kernel<<<dim3(S / 8, D / 256), 256, 0, stream>>>(w1, b1, C1);
    gterm_kernel<<<dim3(B, D / 256), 256, 0, stream>>>(g, w1, gterm);
    zero_kernel<<<(B * S) / 256, 256, 0, stream>>>(score);
    gemm_mfma<<<dim3(4, 512), 256, 0, stream>>>(feat, w1th, w1tl, w2, gterm, C1, score);
    topk_kernel<<<B, 512, 0, stream>>>(score, feat, out_ind, out_sel);
}

// Round 4
// 428.592 us; speedup vs baseline: 1.9648x; 1.2702x over previous
//
#include <hip/hip_runtime.h>
#include <math.h>

#define B 128
#define D 512
#define S 512
#define TOPK 10

typedef short bf16x8 __attribute__((ext_vector_type(8)));
typedef float f32x4 __attribute__((ext_vector_type(4)));
typedef short short4v __attribute__((ext_vector_type(4)));

// -------- workspace layout (floats) --------
// g      @ 0        [65536]
// gterm  @ 65536    [65536]
// score  @ 131072   [65536]     (g/gterm/score zeroed in one pass)
// C1     @ 196608   [262144]
// w1th   @ 458752   [262144]    (512 d x 1024 f bf16)
// w1tl   @ 720896   [262144]
// peh    @ 983040   [262144]    (512 s x 1024 f bf16)
// pel    @ 1245184  [262144]
// total 1507328 floats = 5.75 MB

// ---------------- zero g+gterm+score (192K floats) ----------------
__global__ void zero_kernel(float* __restrict__ p) {
    p[blockIdx.x * 256 + threadIdx.x] = 0.0f;
}

// ---------------- fused transpose + mean ----------------
// feat[b,s,d] = x[b,d,s]; g[b,d] += partial sums over s (atomic)
__global__ __launch_bounds__(256) void transpose_mean_kernel(
    const float* __restrict__ x, float* __restrict__ feat, float* __restrict__ g) {
    __shared__ float tile[64 * 65];  // addr(d,s) = d + s*65  (2-way bank aliasing = free)
    int b = blockIdx.z;
    int s0 = blockIdx.x * 64, d0 = blockIdx.y * 64;
    int t = threadIdx.x;
    int ty = t >> 4, tx = t & 15;
    const float4* x4 = (const float4*)(x + (size_t)b * D * S);
    float psum[4];
#pragma unroll
    for (int q = 0; q < 4; ++q) {
        int d = ty + 16 * q;
        float4 v = x4[(size_t)(d0 + d) * (S / 4) + (s0 >> 2) + tx];
        tile[d + (4 * tx + 0) * 65] = v.x;
        tile[d + (4 * tx + 1) * 65] = v.y;
        tile[d + (4 * tx + 2) * 65] = v.z;
        tile[d + (4 * tx + 3) * 65] = v.w;
        float sm = (v.x + v.y) + (v.z + v.w);
#pragma unroll
        for (int off = 8; off; off >>= 1) sm += __shfl_down(sm, off, 16);
        psum[q] = sm;
    }
    if (tx == 0) {
#pragma unroll
        for (int q = 0; q < 4; ++q)
            atomicAdd(&g[b * D + d0 + ty + 16 * q], psum[q] * (1.0f / S));
    }
    __syncthreads();
    float4* f4 = (float4*)(feat + (size_t)b * S * D);
#pragma unroll
    for (int q = 0; q < 4; ++q) {
        int s = ty + 16 * q;
        float4 o;
        o.x = tile[(4 * tx + 0) + s * 65];
        o.y = tile[(4 * tx + 1) + s * 65];
        o.z = tile[(4 * tx + 2) + s * 65];
        o.w = tile[(4 * tx + 3) + s * 65];
        f4[(size_t)(s0 + s) * (D / 4) + (d0 >> 2) + tx] = o;
    }
}

// ---------------- split fp32 -> (hi bf16 RNE, lo bf16 RZ), packed ----------------
__device__ __forceinline__ unsigned splitf(float f) {
    unsigned u = __float_as_uint(f);
    unsigned rb = u + 0x7FFFu + ((u >> 16) & 1u);  // RNE to bf16
    float hf = __uint_as_float(rb & 0xFFFF0000u);
    unsigned u2 = __float_as_uint(f - hf);  // exact residual
    return (rb >> 16) | (u2 & 0xFFFF0000u);
}

// ---------------- pe precompute + split: pe[s][f], f=2i sin / 2i+1 cos ----------------
__global__ void pe_kernel(ushort* __restrict__ peh, ushort* __restrict__ pel) {
    int s = blockIdx.x, t = threadIdx.x;
#pragma unroll
    for (int q = 0; q < 2; ++q) {
        int i = t + 256 * q;  // 0..511
        float ei = expf((float)(2 * i) * -0.0089944730195f);  // -ln(10000)/1024 * 2i
        float ang = (float)s * ei;
        float sv = sinf(ang), cv = cosf(ang);
        unsigned ps = splitf(sv), pc = splitf(cv);
        size_t base = (size_t)s * 1024 + 2 * i;
        peh[base] = (ushort)(ps & 0xFFFFu);
        peh[base + 1] = (ushort)(pc & 0xFFFFu);
        pel[base] = (ushort)(ps >> 16);
        pel[base + 1] = (ushort)(pc >> 16);
    }
}

// ---------------- w1 full split+transpose: w1t{h,l}[d][f] = split(w1[f][d]), f<1024 ----
__global__ void w1split_kernel(const float* __restrict__ w1, ushort* __restrict__ w1th,
                               ushort* __restrict__ w1tl) {
    __shared__ float tile[32][33];
    int k0 = blockIdx.x * 32, d0 = blockIdx.y * 32;
    int tx = threadIdx.x, ty = threadIdx.y;  // 32 x 8
#pragma unroll
    for (int j = 0; j < 4; ++j)
        tile[ty + j * 8][tx] = w1[(size_t)(k0 + ty + j * 8) * D + d0 + tx];
    __syncthreads();
#pragma unroll
    for (int j = 0; j < 4; ++j) {
        unsigned p = splitf(tile[tx][ty + j * 8]);
        size_t idx = (size_t)(d0 + ty + j * 8) * 1024 + k0 + tx;
        w1th[idx] = (ushort)(p & 0xFFFFu);
        w1tl[idx] = (ushort)(p >> 16);
    }
}

// ---------------- C1 = pe @ w1 + b1 via split-bf16 MFMA, 64x64 tiles, K=1024 ----------
#define CP 40
__global__ __launch_bounds__(256) void c1_mfma(
    const ushort* __restrict__ peh, const ushort* __restrict__ pel,
    const ushort* __restrict__ w1th, const ushort* __restrict__ w1tl,
    const float* __restrict__ b1, float* __restrict__ C1) {
    __shared__ short sAh[64 * CP];
    __shared__ short sAl[64 * CP];
    __shared__ short sBh[64 * CP];
    __shared__ short sBl[64 * CP];
    int t = threadIdx.x;
    int d0 = blockIdx.x * 64, s0 = blockIdx.y * 64;
    int w = t >> 6, l = t & 63, lc = l & 15, lg = l >> 4;
    int tm = t >> 2, tk = (t & 3) * 8;
    f32x4 acc[4] = {};
    for (int k0 = 0; k0 < 1024; k0 += 32) {
        __syncthreads();
        *(bf16x8*)(sAh + tm * CP + tk) = *(const bf16x8*)(peh + (size_t)(s0 + tm) * 1024 + k0 + tk);
        *(bf16x8*)(sAl + tm * CP + tk) = *(const bf16x8*)(pel + (size_t)(s0 + tm) * 1024 + k0 + tk);
        *(bf16x8*)(sBh + tm * CP + tk) = *(const bf16x8*)(w1th + (size_t)(d0 + tm) * 1024 + k0 + tk);
        *(bf16x8*)(sBl + tm * CP + tk) = *(const bf16x8*)(w1tl + (size_t)(d0 + tm) * 1024 + k0 + tk);
        __syncthreads();
        int m = w * 16 + lc;
        bf16x8 ah = *(const bf16x8*)(sAh + m * CP + lg * 8);
        bf16x8 al = *(const bf16x8*)(sAl + m * CP + lg * 8);
#pragma unroll
        for (int j = 0; j < 4; ++j) {
            int n = j * 16 + lc;
            bf16x8 bh = *(const bf16x8*)(sBh + n * CP + lg * 8);
            bf16x8 bl = *(const bf16x8*)(sBl + n * CP + lg * 8);
            acc[j] = __builtin_amdgcn_mfma_f32_16x16x32_bf16(ah, bh, acc[j], 0, 0, 0);
            acc[j] = __builtin_amdgcn_mfma_f32_16x16x32_bf16(ah, bl, acc[j], 0, 0, 0);
            acc[j] = __builtin_amdgcn_mfma_f32_16x16x32_bf16(al, bh, acc[j], 0, 0, 0);
        }
    }
#pragma unroll
    for (int j = 0; j < 4; ++j)
#pragma unroll
        for (int reg = 0; reg < 4; ++reg) {
            int sg = s0 + w * 16 + lg * 4 + reg;
            int dg = d0 + j * 16 + lc;
            C1[(size_t)sg * D + dg] = acc[j][reg] + b1[dg];
        }
}

// ---------------- gterm[b,d] += sum_{k in chunk} g[b,k] * w1[D+k, d] ----------------
__global__ void gterm_kernel(const float* __restrict__ g, const float* __restrict__ w1,
                             float* __restrict__ gterm) {
    int b = blockIdx.x;
    int d = blockIdx.y * 256 + threadIdx.x;
    int kc = blockIdx.z * 128;
    const float* gb = g + b * D + kc;
    float a0 = 0.f, a1 = 0.f, a2 = 0.f, a3 = 0.f;
    for (int k = 0; k < 128; k += 4) {
        a0 += gb[k + 0] * w1[(size_t)(D + kc + k + 0) * D + d];
        a1 += gb[k + 1] * w1[(size_t)(D + kc + k + 1) * D + d];
        a2 += gb[k + 2] * w1[(size_t)(D + kc + k + 2) * D + d];
        a3 += gb[k + 3] * w1[(size_t)(D + kc + k + 3) * D + d];
    }
    atomicAdd(&gterm[b * D + d], (a0 + a1) + (a2 + a3));
}

// ---------------- split-bf16 MFMA GEMM + fused ReLU + w2-dot -> atomic score ----
#define GP 40
__global__ __launch_bounds__(256, 2) void gemm_mfma(
    const float* __restrict__ feat, const ushort* __restrict__ w1th,
    const ushort* __restrict__ w1tl, const float* __restrict__ w2,
    const float* __restrict__ gterm, const float* __restrict__ C1,
    float* __restrict__ score) {
    __shared__ short sAh[128 * GP];
    __shared__ short sAl[128 * GP];
    __shared__ short sBh[128 * GP];
    __shared__ short sBl[128 * GP];
    int t = threadIdx.x;
    int d0 = blockIdx.x * 128;
    int row0 = blockIdx.y * 128;
    int b = row0 >> 9;
    int tm = t >> 3, tk4 = t & 7;
    int w = t >> 6, l = t & 63;
    int wr = w >> 1, wc = w & 1;
    int lc = l & 15, lg = l >> 4;

    f32x4 acc[4][4] = {};

    for (int k0 = 0; k0 < D; k0 += 32) {
        __syncthreads();
#pragma unroll
        for (int q = 0; q < 4; ++q) {
            int m = tm + 32 * q;
            const float4 v = *(const float4*)(feat + (size_t)(row0 + m) * D + k0 + tk4 * 4);
            unsigned p0 = splitf(v.x), p1 = splitf(v.y), p2 = splitf(v.z), p3 = splitf(v.w);
            short4v hi, lo;
            hi[0] = (short)(p0 & 0xFFFFu); lo[0] = (short)(p0 >> 16);
            hi[1] = (short)(p1 & 0xFFFFu); lo[1] = (short)(p1 >> 16);
            hi[2] = (short)(p2 & 0xFFFFu); lo[2] = (short)(p2 >> 16);
            hi[3] = (short)(p3 & 0xFFFFu); lo[3] = (short)(p3 >> 16);
            *(short4v*)(sAh + m * GP + tk4 * 4) = hi;
            *(short4v*)(sAl + m * GP + tk4 * 4) = lo;
            size_t widx = (size_t)(d0 + m) * 1024 + k0 + tk4 * 4;
            *(short4v*)(sBh + m * GP + tk4 * 4) = *(const short4v*)(w1th + widx);
            *(short4v*)(sBl + m * GP + tk4 * 4) = *(const short4v*)(w1tl + widx);
        }
        __syncthreads();
        bf16x8 ah[4], al[4], bh[4], bl[4];
#pragma unroll
        for (int i = 0; i < 4; ++i) {
            int m = wr * 64 + i * 16 + lc;
            ah[i] = *(const bf16x8*)(sAh + m * GP + lg * 8);
            al[i] = *(const bf16x8*)(sAl + m * GP + lg * 8);
            int n = wc * 64 + i * 16 + lc;
            bh[i] = *(const bf16x8*)(sBh + n * GP + lg * 8);
            bl[i] = *(const bf16x8*)(sBl + n * GP + lg * 8);
        }
#pragma unroll
        for (int i = 0; i < 4; ++i)
#pragma unroll
            for (int j = 0; j < 4; ++j) {
                acc[i][j] = __builtin_amdgcn_mfma_f32_16x16x32_bf16(ah[i], bh[j], acc[i][j], 0, 0, 0);
                acc[i][j] = __builtin_amdgcn_mfma_f32_16x16x32_bf16(ah[i], bl[j], acc[i][j], 0, 0, 0);
                acc[i][j] = __builtin_amdgcn_mfma_f32_16x16x32_bf16(al[i], bh[j], acc[i][j], 0, 0, 0);
            }
    }
    float w2v[4], gt[4];
#pragma unroll
    for (int j = 0; j < 4; ++j) {
        int d = d0 + wc * 64 + j * 16 + lc;
        w2v[j] = w2[d];
        gt[j] = gterm[b * D + d];
    }
#pragma unroll
    for (int i = 0; i < 4; ++i)
#pragma unroll
        for (int reg = 0; reg < 4; ++reg) {
            int srow = row0 + wr * 64 + i * 16 + lg * 4 + reg;
            int s = srow & 511;
            float part = 0.f;
#pragma unroll
            for (int j = 0; j < 4; ++j) {
                int d = d0 + wc * 64 + j * 16 + lc;
                float z = acc[i][j][reg] + gt[j] + C1[(size_t)s * D + d];
                part += w2v[j] * fmaxf(z, 0.f);
            }
#pragma unroll
            for (int off = 8; off; off >>= 1) part += __shfl_down(part, off, 16);
            if (lc == 0) atomicAdd(&score[srow], part);
        }
}

// ---------------- per-batch top-10 + one-hot + gather ----------------
__global__ void topk_kernel(const float* __restrict__ score, const float* __restrict__ feat,
                            float* __restrict__ out_ind, float* __restrict__ out_sel) {
    __shared__ float work[512];
    __shared__ float wv[8];
    __shared__ int wi[8];
    __shared__ int topi[TOPK];
    int b = blockIdx.x, t = threadIdx.x;
    work[t] = score[b * S + t];
    __syncthreads();
    for (int it = 0; it < TOPK; ++it) {
        float v = work[t];
        int i = t;
#pragma unroll
        for (int off = 32; off; off >>= 1) {
            float ov = __shfl_down(v, off);
            int oi = __shfl_down(i, off);
            if (ov > v || (ov == v && oi < i)) { v = ov; i = oi; }
        }
        if ((t & 63) == 0) { wv[t >> 6] = v; wi[t >> 6] = i; }
        __syncthreads();
        if (t == 0) {
            float bv = wv[0];
            int bi = wi[0];
            for (int w = 1; w < 8; ++w)
                if (wv[w] > bv || (wv[w] == bv && wi[w] < bi)) { bv = wv[w]; bi = wi[w]; }
            topi[it] = bi;
            work[bi] = -INFINITY;
        }
        __syncthreads();
    }
    if (t == 0) {
        for (int a = 1; a < TOPK; ++a) {
            int key = topi[a];
            int c = a - 1;
            while (c >= 0 && topi[c] > key) { topi[c + 1] = topi[c]; --c; }
            topi[c + 1] = key;
        }
    }
    __syncthreads();
    float* oi_b = out_ind + (size_t)b * TOPK * S;
#pragma unroll
    for (int k = 0; k < TOPK; ++k) oi_b[k * S + t] = 0.0f;
    __syncthreads();
    if (t < TOPK) oi_b[t * S + topi[t]] = 1.0f;
    float* os_b = out_sel + (size_t)b * TOPK * D;
    const float* fb = feat + (size_t)b * S * D;
#pragma unroll
    for (int k = 0; k < TOPK; ++k) os_b[k * D + t] = fb[(size_t)topi[k] * D + t];
}

extern "C" void kernel_launch(void* const* d_in, const int* in_sizes, int n_in,
                              void* d_out, int out_size, void* d_ws, size_t ws_size,
                              hipStream_t stream) {
    const float* x  = (const float*)d_in[0];
    const float* w1 = (const float*)d_in[1];
    const float* b1 = (const float*)d_in[2];
    const float* w2 = (const float*)d_in[3];
    // b2 (d_in[4]): uniform score shift, ranking-invariant -> dropped.

    float* out = (float*)d_out;
    float* out_ind = out;                              // [B,10,S]
    float* out_sel = out + (size_t)B * TOPK * S;       // [B,10,D]
    float* feat    = out + 2 * (size_t)B * TOPK * S;   // [B,S,D]

    float* ws     = (float*)d_ws;
    float* g      = ws;                       // [B*D]
    float* gterm  = ws + 65536;               // [B*D]
    float* score  = ws + 131072;              // [B*S]
    float* C1     = ws + 196608;              // [S*D]
    ushort* w1th  = (ushort*)(ws + 458752);   // [512][1024] bf16
    ushort* w1tl  = (ushort*)(ws + 720896);
    ushort* peh   = (ushort*)(ws + 983040);   // [512][1024] bf16
    ushort* pel   = (ushort*)(ws + 1245184);

    zero_kernel<<<768, 256, 0, stream>>>(ws);  // g + gterm + score
    transpose_mean_kernel<<<dim3(8, 8, B), 256, 0, stream>>>(x, feat, g);
    gterm_kernel<<<dim3(B, 2, 4), 256, 0, stream>>>(g, w1, gterm);
    pe_kernel<<<S, 256, 0, stream>>>(peh, pel);
    w1split_kernel<<<dim3(32, 16), dim3(32, 8), 0, stream>>>(w1, w1th, w1tl);
    c1_mfma<<<dim3(8, 8), 256, 0, stream>>>(peh, pel, w1th, w1tl, b1, C1);
    gemm_mfma<<<dim3(4, 512), 256, 0, stream>>>(feat, w1th, w1tl, w2, gterm, C1, score);
    topk_kernel<<<B, 512, 0, stream>>>(score, feat, out_ind, out_sel);
}